// Round 6
// baseline (299.771 us; speedup 1.0000x reference)
//
#include <hip/hip_runtime.h>
#include <hip/hip_bf16.h>

typedef __bf16 bf16_t;
typedef __bf16 bf16x8 __attribute__((ext_vector_type(8)));
typedef __bf16 bf16x4 __attribute__((ext_vector_type(4)));
typedef float f32x4 __attribute__((ext_vector_type(4)));
typedef float f32x16 __attribute__((ext_vector_type(16)));

#define HIDDEN 2048
#define NHEADS 16
#define HD 128
#define NTOK 2048
#define BATCH 2
#define MROWS (BATCH*NTOK)
#define QKVCOLS (3*HIDDEN)

__device__ __forceinline__ void gload16(const void* g, void* l) {
    __builtin_amdgcn_global_load_lds(
        (const __attribute__((address_space(1))) void*)g,
        (__attribute__((address_space(3))) void*)l,
        16, 0, 0);
}

__device__ __forceinline__ unsigned int pack2bf(float lo, float hi2) {
    union { bf16_t h[2]; unsigned int u; } t;
    t.h[0] = (bf16_t)lo; t.h[1] = (bf16_t)hi2;
    return t.u;
}

// ---------------- fp32 -> bf16 elementwise (x) ----------------
__global__ __launch_bounds__(256) void cvt8_kernel(const float* __restrict__ in,
                                                   bf16_t* __restrict__ out, int n8) {
    int i = blockIdx.x * blockDim.x + threadIdx.x;
    if (i >= n8) return;
    const float4 a = *(const float4*)(in + (size_t)i * 8);
    const float4 b = *(const float4*)(in + (size_t)i * 8 + 4);
    bf16x8 r;
    r[0] = (bf16_t)a.x; r[1] = (bf16_t)a.y; r[2] = (bf16_t)a.z; r[3] = (bf16_t)a.w;
    r[4] = (bf16_t)b.x; r[5] = (bf16_t)b.y; r[6] = (bf16_t)b.z; r[7] = (bf16_t)b.w;
    *(bf16x8*)(out + (size_t)i * 8) = r;
}

// ---------------- fp32 KxN -> bf16 NxK transpose-convert ----------------
__global__ __launch_bounds__(256) void cvtT_kernel(const float* __restrict__ in,
                                                   bf16_t* __restrict__ out, int K, int N) {
    __shared__ float t[64][65];
    const int n0 = blockIdx.x * 64, k0 = blockIdx.y * 64;
    const int tid = threadIdx.x, c = tid & 63, r4 = tid >> 6;
#pragma unroll
    for (int rr = 0; rr < 64; rr += 4)
        t[rr + r4][c] = in[(size_t)(k0 + rr + r4) * N + n0 + c];
    __syncthreads();
#pragma unroll
    for (int rr = 0; rr < 64; rr += 4) {
        int nn = rr + r4;
        out[(size_t)(n0 + nn) * K + k0 + c] = (bf16_t)t[c][nn];
    }
}

// ---------------- 3-buffer pipelined GEMM: C[M][N] = A * Bt^T + bias ----------------
// 128x256 tile, BK=32, 4 waves, 3 LDS bufs (depth-2 staging), counted vmcnt(6),
// raw s_barrier once per K-tile, T2 XOR-swizzle (0 conflicts), T5 setprio.
// n-major XCD swizzle: each 256-col B-panel (1MB) stays hot in its XCD's L2.
template <typename OUTT>
__global__ __launch_bounds__(256, 2) void gemm_pipe(const bf16_t* __restrict__ A,
                                                    const bf16_t* __restrict__ Bt,
                                                    const float* __restrict__ bias,
                                                    OUTT* __restrict__ C,
                                                    int M, int N, int K) {
    __shared__ __align__(16) char lds[3][24576];  // per buf: A 8KB | B 16KB
    const int NKT = K >> 5;
    const int tid = threadIdx.x, wid = tid >> 6, lane = tid & 63;
    const int lr = lane & 15, lg = lane >> 4;
    const int nwg = gridDim.x, cpx = nwg >> 3;
    const int bid = blockIdx.x;
    const int swz = (bid & 7) * cpx + (bid >> 3);
    const int ntm = M >> 7;
    const int m0 = (swz % ntm) * 128, n0 = (swz / ntm) * 256;

    const int sc = (((tid & 3) ^ ((tid >> 3) & 3)) << 4);
    const int srow = tid >> 2;
    const char* pA0 = (const char*)A + ((size_t)(m0 + srow) * K) * 2 + sc;
    const char* pA1 = (const char*)A + ((size_t)(m0 + srow + 64) * K) * 2 + sc;
    const char* pB0 = (const char*)Bt + ((size_t)(n0 + srow) * K) * 2 + sc;
    const char* pB1 = (const char*)Bt + ((size_t)(n0 + srow + 64) * K) * 2 + sc;
    const char* pB2 = (const char*)Bt + ((size_t)(n0 + srow + 128) * K) * 2 + sc;
    const char* pB3 = (const char*)Bt + ((size_t)(n0 + srow + 192) * K) * 2 + sc;
    const int xoff = lr * 64 + ((lg ^ ((lr >> 1) & 3)) << 4);

    auto stage3a = [&](int kb, char* bp) {
        gload16(pA0 + kb, bp + tid * 16);
        gload16(pA1 + kb, bp + tid * 16 + 4096);
        gload16(pB0 + kb, bp + 8192 + tid * 16);
    };
    auto stage3b = [&](int kb, char* bp) {
        gload16(pB1 + kb, bp + 8192 + tid * 16 + 4096);
        gload16(pB2 + kb, bp + 8192 + tid * 16 + 8192);
        gload16(pB3 + kb, bp + 8192 + tid * 16 + 12288);
    };

    f32x4 acc[8][4];
#pragma unroll
    for (int m = 0; m < 8; ++m)
#pragma unroll
        for (int n = 0; n < 4; ++n) acc[m][n] = f32x4{0.f, 0.f, 0.f, 0.f};

    stage3a(0, lds[0]); stage3b(0, lds[0]);
    stage3a(64, lds[1]); stage3b(64, lds[1]);
    asm volatile("s_waitcnt vmcnt(6)" ::: "memory");
    __builtin_amdgcn_s_barrier();

    int cur = 0;
    for (int kt = 0; kt < NKT; ++kt) {
        const char* Al = lds[cur];
        const char* Bl = Al + 8192;
        int sb = cur + 2; if (sb >= 3) sb -= 3;
        char* sp = lds[sb];
        const bool st = (kt + 2) < NKT;
        const int kb = (kt + 2) << 6;

        bf16x8 bfr[4], afr[4];
#pragma unroll
        for (int n = 0; n < 4; ++n)
            bfr[n] = *(const bf16x8*)(Bl + wid * 4096 + n * 1024 + xoff);
#pragma unroll
        for (int m = 0; m < 4; ++m)
            afr[m] = *(const bf16x8*)(Al + m * 1024 + xoff);
        if (st) stage3a(kb, sp);
        __builtin_amdgcn_s_setprio(1);
#pragma unroll
        for (int m = 0; m < 4; ++m)
#pragma unroll
            for (int n = 0; n < 4; ++n)
                acc[m][n] = __builtin_amdgcn_mfma_f32_16x16x32_bf16(afr[m], bfr[n], acc[m][n], 0, 0, 0);
        __builtin_amdgcn_s_setprio(0);

#pragma unroll
        for (int m = 0; m < 4; ++m)
            afr[m] = *(const bf16x8*)(Al + (m + 4) * 1024 + xoff);
        if (st) stage3b(kb, sp);
        __builtin_amdgcn_s_setprio(1);
#pragma unroll
        for (int m = 0; m < 4; ++m)
#pragma unroll
            for (int n = 0; n < 4; ++n)
                acc[m + 4][n] = __builtin_amdgcn_mfma_f32_16x16x32_bf16(afr[m], bfr[n], acc[m + 4][n], 0, 0, 0);
        __builtin_amdgcn_s_setprio(0);

        if (kt < NKT - 1) {
            if (st) asm volatile("s_waitcnt vmcnt(6)" ::: "memory");
            else    asm volatile("s_waitcnt vmcnt(0)" ::: "memory");
            __builtin_amdgcn_s_barrier();
        }
        cur = cur + 1; if (cur >= 3) cur -= 3;
    }

    float bvals[4];
#pragma unroll
    for (int n = 0; n < 4; ++n) bvals[n] = bias[n0 + wid * 64 + n * 16 + lr];
#pragma unroll
    for (int m = 0; m < 8; ++m) {
        const size_t row = (size_t)(m0 + m * 16 + lg * 4);
#pragma unroll
        for (int n = 0; n < 4; ++n) {
            const int col = n0 + wid * 64 + n * 16 + lr;
#pragma unroll
            for (int i = 0; i < 4; ++i)
                C[(row + i) * N + col] = (OUTT)(acc[m][n][i] + bvals[n]);
        }
    }
}

// ---------------- cos/sin table: tab[n][j] = (cos, sin), 2048 x 64 ----------------
__global__ __launch_bounds__(256) void rope_cs(const int* __restrict__ Hp,
                                               const int* __restrict__ Wp,
                                               float2* __restrict__ tab) {
    const int idx = blockIdx.x * 256 + threadIdx.x;  // 512 blocks
    const int n = idx >> 6, j = idx & 63;
    const int Hh = *Hp, Ww = *Wp, HW = Hh * Ww;
    const int t = n / HW, rem = n % HW;
    const int hh = rem / Ww, w = rem % Ww;
    float pos = (j < 16) ? (float)t : (j < 40 ? (float)hh : (float)w);
    float inv = expf(-(float)j * (9.210340371976184f / 64.f));
    float ang = pos * inv;
    tab[idx] = make_float2(cosf(ang), sinf(ang));
}

// ---------------- fused MRoPE (q,k) + v transpose (table-driven) ----------------
__global__ __launch_bounds__(256) void rope_fused(const bf16_t* __restrict__ qkv,
                                                  bf16_t* __restrict__ qT,
                                                  bf16_t* __restrict__ kT,
                                                  bf16_t* __restrict__ vT,
                                                  const float2* __restrict__ tab) {
    const int blk = blockIdx.x;          // 1024 = 32 bh x 32 token-tiles
    const int bh = blk >> 5;
    const int n0 = (blk & 31) * 64;
    const int b = bh >> 4, h = bh & 15;
    const int tid = threadIdx.x;
    __shared__ bf16_t vt[64][132];       // [tok][d], +4 pad

    const float qscale = 0.08838834764831845f;  // 1/sqrt(128)
    const int jg = tid & 7, tn = tid >> 3;      // 32 tokens per pass
#pragma unroll
    for (int p = 0; p < 2; ++p) {
        const int tok = p * 32 + tn, n = n0 + tok;
        const bf16_t* base = qkv + (size_t)(b * NTOK + n) * QKVCOLS + h * HD + jg * 8;
        bf16x8 q1 = *(const bf16x8*)(base);
        bf16x8 q2 = *(const bf16x8*)(base + 64);
        bf16x8 k1 = *(const bf16x8*)(base + 2048);
        bf16x8 k2 = *(const bf16x8*)(base + 2048 + 64);
        bf16x8 v1 = *(const bf16x8*)(base + 4096);
        bf16x8 v2 = *(const bf16x8*)(base + 4096 + 64);
        union { float4 f4[4]; float2 f2[8]; } cs;
        const float4* cp4 = (const float4*)(tab + (size_t)n * 64 + jg * 8);
#pragma unroll
        for (int i = 0; i < 4; ++i) cs.f4[i] = cp4[i];
        bf16x8 oq1, oq2, ok1, ok2;
#pragma unroll
        for (int i = 0; i < 8; ++i) {
            float c = cs.f2[i].x, s = cs.f2[i].y;
            float a = (float)q1[i], bb = (float)q2[i];
            oq1[i] = (bf16_t)((a * c - bb * s) * qscale);
            oq2[i] = (bf16_t)((bb * c + a * s) * qscale);
            a = (float)k1[i]; bb = (float)k2[i];
            ok1[i] = (bf16_t)(a * c - bb * s);
            ok2[i] = (bf16_t)(bb * c + a * s);
        }
        const size_t qo = ((size_t)bh * NTOK + n) * HD + jg * 8;
        *(bf16x8*)(qT + qo) = oq1;
        *(bf16x8*)(qT + qo + 64) = oq2;
        *(bf16x8*)(kT + qo) = ok1;
        *(bf16x8*)(kT + qo + 64) = ok2;
        *(bf16x8*)&vt[tok][jg * 8] = v1;
        *(bf16x8*)&vt[tok][jg * 8 + 64] = v2;
    }
    __syncthreads();

    // vT[bh][d][NTOK]: thread (d = tid>>1, half = tid&1) writes 32 tokens
    const int d = tid >> 1, th = (tid & 1) * 32;
    bf16_t* orow = vT + ((size_t)bh * HD + d) * NTOK + n0 + th;
#pragma unroll
    for (int c = 0; c < 4; ++c) {
        bf16x8 tmp;
#pragma unroll
        for (int e = 0; e < 8; ++e) tmp[e] = vt[th + c * 8 + e][d];
        *(bf16x8*)(orow + c * 8) = tmp;
    }
}

// ---------------- flash attention: 4 waves x 32 q-rows, 32x32 MFMA ----------------
__global__ __launch_bounds__(256, 2) void attn_kernel(const bf16_t* __restrict__ qT,
                                                      const bf16_t* __restrict__ kT,
                                                      const bf16_t* __restrict__ vT,
                                                      bf16_t* __restrict__ outp) {
    __shared__ __align__(16) char lds[2][32768];  // per buf: K tile 16KB | V tile 16KB
    const int B = blockIdx.x;
    const int xcd = B & 7, jj = B >> 3;
    const int bh = xcd * 4 + (jj >> 4);
    const int q0 = (jj & 15) * 128;
    const int tid = threadIdx.x, wid = tid >> 6, lane = tid & 63;
    const int ql = lane & 31, hi = lane >> 5;

    const bf16_t* Q = qT + (size_t)bh * NTOK * HD;
    const char* Kb = (const char*)(kT + (size_t)bh * NTOK * HD);
    const char* Vb = (const char*)(vT + (size_t)bh * NTOK * HD);

    bf16x8 qf[8];
    {
        const bf16_t* qrow = Q + (size_t)(q0 + wid * 32 + ql) * HD + hi * 8;
#pragma unroll
        for (int kc = 0; kc < 8; ++kc) qf[kc] = *(const bf16x8*)(qrow + kc * 16);
    }
    f32x16 oa[4];
#pragma unroll
    for (int df = 0; df < 4; ++df)
#pragma unroll
        for (int r = 0; r < 16; ++r) oa[df][r] = 0.f;
    float m_run = -1e30f, l_run = 0.f;
    const float L2E = 1.44269504089f;

    auto stage = [&](int t, int buf) {
#pragma unroll
        for (int i = 0; i < 4; ++i) {
            int a = wid * 4096 + i * 1024 + lane * 16;
            int row = a >> 8;
            int col = (a & 255) ^ ((row & 7) << 4);
            gload16(Kb + (size_t)(t * 64 + row) * 256 + col,
                    (char*)lds[buf] + wid * 4096 + i * 1024);
        }
#pragma unroll
        for (int i = 0; i < 4; ++i) {
            int a = wid * 4096 + i * 1024 + lane * 16;
            int row = a >> 7;
            int col = (a & 127) ^ ((row & 7) << 4);
            gload16(Vb + (size_t)row * (NTOK * 2) + t * 128 + col,
                    (char*)lds[buf] + 16384 + wid * 4096 + i * 1024);
        }
    };
    stage(0, 0);
    __syncthreads();

    for (int t = 0; t < NTOK / 64; ++t) {
        if (t < NTOK / 64 - 1) stage(t + 1, (t + 1) & 1);
        const char* Kl = lds[t & 1];
        const char* Vl = Kl + 16384;

        f32x16 s[2];
#pragma unroll
        for (int nb = 0; nb < 2; ++nb) {
#pragma unroll
            for (int r = 0; r < 16; ++r) s[nb][r] = 0.f;
            int row = nb * 32 + ql;
            const char* krow = Kl + row * 256;
            int sw = (row & 7) << 4;
            __builtin_amdgcn_s_setprio(1);
#pragma unroll
            for (int kc = 0; kc < 8; ++kc) {
                bf16x8 kf = *(const bf16x8*)(krow + ((kc * 32 + hi * 16) ^ sw));
                s[nb] = __builtin_amdgcn_mfma_f32_32x32x16_bf16(kf, qf[kc], s[nb], 0, 0, 0);
            }
            __builtin_amdgcn_s_setprio(0);
        }

        // ---- tree max (depth 5, independent ops) ----
        float t16[16];
#pragma unroll
        for (int r = 0; r < 16; ++r) t16[r] = fmaxf(s[0][r], s[1][r]);
#pragma unroll
        for (int st = 8; st >= 1; st >>= 1)
#pragma unroll
            for (int r = 0; r < st; ++r) t16[r] = fmaxf(t16[r], t16[r + st]);
        float mx = fmaxf(t16[0], __shfl_xor(t16[0], 32));
        if (__any(mx - m_run > 8.f)) {
            float mn = fmaxf(m_run, mx);
            float resc = __expf(m_run - mn);
            l_run *= resc;
#pragma unroll
            for (int df = 0; df < 4; ++df) oa[df] *= resc;
            m_run = mn;
        }
        // ---- exp2-fused P, tree sum ----
        const float mb = m_run * L2E;
#pragma unroll
        for (int nb = 0; nb < 2; ++nb)
#pragma unroll
            for (int r = 0; r < 16; ++r)
                s[nb][r] = exp2f(fmaf(s[nb][r], L2E, -mb));
        float u16[16];
#pragma unroll
        for (int r = 0; r < 16; ++r) u16[r] = s[0][r] + s[1][r];
#pragma unroll
        for (int st = 8; st >= 1; st >>= 1)
#pragma unroll
            for (int r = 0; r < st; ++r) u16[r] += u16[r + st];
        float rs = u16[0] + __shfl_xor(u16[0], 32);
        l_run += rs;

        unsigned int pk[2][8];
#pragma unroll
        for (int nb = 0; nb < 2; ++nb)
#pragma unroll
            for (int m = 0; m < 8; ++m) pk[nb][m] = pack2bf(s[nb][2 * m], s[nb][2 * m + 1]);

#pragma unroll
        for (int kc2 = 0; kc2 < 4; ++kc2) {
            const int nb = kc2 >> 1, c1 = kc2 & 1;
            union { unsigned int u[4]; bf16x8 v; } pb;
#pragma unroll
            for (int j = 0; j < 4; ++j) {
                const int bsel = (j & 1) + 4 * c1;
                unsigned int vlo = pk[nb][bsel];
                unsigned int vhi = pk[nb][bsel + 2];
                unsigned int mine = hi ? vhi : vlo;
                unsigned int yours = hi ? vlo : vhi;
                unsigned int x = (unsigned int)__shfl_xor((int)yours, 32);
                pb.u[j] = (hi == (j >> 1)) ? mine : x;
            }
            __builtin_amdgcn_s_setprio(1);
#pragma unroll
            for (int df = 0; df < 4; ++df) {
                int row = df * 32 + ql;
                bf16x8 va = *(const bf16x8*)(Vl + row * 128 + ((kc2 * 32 + hi * 16) ^ ((row & 7) << 4)));
                oa[df] = __builtin_amdgcn_mfma_f32_32x32x16_bf16(va, pb.v, oa[df], 0, 0, 0);
            }
            __builtin_amdgcn_s_setprio(0);
        }
        __syncthreads();
    }

    float inv = 1.f / l_run;
    bf16_t* Ot = (bf16_t*)((char*)lds + wid * 8704);
#pragma unroll
    for (int df = 0; df < 4; ++df)
#pragma unroll
        for (int rg = 0; rg < 4; ++rg) {
            bf16x4 w;
#pragma unroll
            for (int i = 0; i < 4; ++i) w[i] = (bf16_t)(oa[df][rg * 4 + i] * inv);
            int d0 = df * 32 + rg * 8 + hi * 4;
            *(bf16x4*)&Ot[ql * 136 + d0] = w;
        }
    __builtin_amdgcn_s_waitcnt(0);
    const int qloc = lane >> 1, half = lane & 1;
    const int b = bh >> 4, h = bh & 15;
    bf16_t* orow = outp + (size_t)(b * NTOK + q0 + wid * 32 + qloc) * HIDDEN + h * HD + half * 64;
    const bf16_t* src = Ot + qloc * 136 + half * 64;
#pragma unroll
    for (int c = 0; c < 8; ++c)
        *(bf16x8*)(orow + c * 8) = *(const bf16x8*)(src + c * 8);
}

extern "C" void kernel_launch(void* const* d_in, const int* in_sizes, int n_in,
                              void* d_out, int out_size, void* d_ws, size_t ws_size,
                              hipStream_t stream) {
    const float* x = (const float*)d_in[0];
    const float* w_qkv = (const float*)d_in[1];
    const float* b_qkv = (const float*)d_in[2];
    const float* w_proj = (const float*)d_in[3];
    const float* b_proj = (const float*)d_in[4];
    const int* Hp = (const int*)d_in[6];
    const int* Wp = (const int*)d_in[7];
    float* out = (float*)d_out;

    char* ws = (char*)d_ws;
    bf16_t* xb = (bf16_t*)(ws + 0);                       // 16 MiB  [4096][2048]
    bf16_t* wqkvT = (bf16_t*)(ws + 16777216);             // 24 MiB  [6144][2048]
    bf16_t* wprojT = (bf16_t*)(ws + 41943040);            // 8 MiB   [2048][2048]
    bf16_t* qkv = (bf16_t*)(ws + 50331648);               // 48 MiB  [4096][6144]
    bf16_t* qTb = (bf16_t*)(ws + 100663296);              // 16 MiB  [32][2048][128]
    bf16_t* kTb = (bf16_t*)(ws + 117440512);              // 16 MiB
    float2* tab = (float2*)(ws + 0);                      // 1 MiB, reuse xb after gemm1
    bf16_t* vT = (bf16_t*)(ws + 16777216);                // reuse wqkvT region after gemm1
    bf16_t* attno = (bf16_t*)(ws + 50331648);             // reuse qkv region after rope

    cvt8_kernel<<<4096, 256, 0, stream>>>(x, xb, 1048576);
    cvtT_kernel<<<dim3(96, 32), 256, 0, stream>>>(w_qkv, wqkvT, 2048, 6144);
    cvtT_kernel<<<dim3(32, 32), 256, 0, stream>>>(w_proj, wprojT, 2048, 2048);
    gemm_pipe<bf16_t><<<768, 256, 0, stream>>>(xb, wqkvT, b_qkv, qkv, MROWS, QKVCOLS, HIDDEN);
    rope_cs<<<512, 256, 0, stream>>>(Hp, Wp, tab);
    rope_fused<<<1024, 256, 0, stream>>>(qkv, qTb, kTb, vT, tab);
    attn_kernel<<<512, 256, 0, stream>>>(qTb, kTb, vT, attno);
    gemm_pipe<float><<<256, 256, 0, stream>>>(attno, wprojT, b_proj, out, MROWS, HIDDEN, HIDDEN);
}

// Round 7
// 293.863 us; speedup vs baseline: 1.0201x; 1.0201x over previous
//
#include <hip/hip_runtime.h>
#include <hip/hip_bf16.h>

typedef __bf16 bf16_t;
typedef __bf16 bf16x8 __attribute__((ext_vector_type(8)));
typedef __bf16 bf16x4 __attribute__((ext_vector_type(4)));
typedef float f32x4 __attribute__((ext_vector_type(4)));
typedef float f32x16 __attribute__((ext_vector_type(16)));

#define HIDDEN 2048
#define NHEADS 16
#define HD 128
#define NTOK 2048
#define BATCH 2
#define MROWS (BATCH*NTOK)
#define QKVCOLS (3*HIDDEN)

__device__ __forceinline__ void gload16(const void* g, void* l) {
    __builtin_amdgcn_global_load_lds(
        (const __attribute__((address_space(1))) void*)g,
        (__attribute__((address_space(3))) void*)l,
        16, 0, 0);
}

__device__ __forceinline__ unsigned int pack2bf(float lo, float hi2) {
    union { bf16_t h[2]; unsigned int u; } t;
    t.h[0] = (bf16_t)lo; t.h[1] = (bf16_t)hi2;
    return t.u;
}

// ---------------- fp32 -> bf16 elementwise (x) ----------------
__global__ __launch_bounds__(256) void cvt8_kernel(const float* __restrict__ in,
                                                   bf16_t* __restrict__ out, int n8) {
    int i = blockIdx.x * blockDim.x + threadIdx.x;
    if (i >= n8) return;
    const float4 a = *(const float4*)(in + (size_t)i * 8);
    const float4 b = *(const float4*)(in + (size_t)i * 8 + 4);
    bf16x8 r;
    r[0] = (bf16_t)a.x; r[1] = (bf16_t)a.y; r[2] = (bf16_t)a.z; r[3] = (bf16_t)a.w;
    r[4] = (bf16_t)b.x; r[5] = (bf16_t)b.y; r[6] = (bf16_t)b.z; r[7] = (bf16_t)b.w;
    *(bf16x8*)(out + (size_t)i * 8) = r;
}

// ---------------- fp32 KxN -> bf16 NxK transpose-convert ----------------
__global__ __launch_bounds__(256) void cvtT_kernel(const float* __restrict__ in,
                                                   bf16_t* __restrict__ out, int K, int N) {
    __shared__ float t[64][65];
    const int n0 = blockIdx.x * 64, k0 = blockIdx.y * 64;
    const int tid = threadIdx.x, c = tid & 63, r4 = tid >> 6;
#pragma unroll
    for (int rr = 0; rr < 64; rr += 4)
        t[rr + r4][c] = in[(size_t)(k0 + rr + r4) * N + n0 + c];
    __syncthreads();
#pragma unroll
    for (int rr = 0; rr < 64; rr += 4) {
        int nn = rr + r4;
        out[(size_t)(n0 + nn) * K + k0 + c] = (bf16_t)t[c][nn];
    }
}

// ---------------- 3-buffer pipelined GEMM: 128x256 tile (QKV proj) ----------------
template <typename OUTT>
__global__ __launch_bounds__(256, 2) void gemm_pipe(const bf16_t* __restrict__ A,
                                                    const bf16_t* __restrict__ Bt,
                                                    const float* __restrict__ bias,
                                                    OUTT* __restrict__ C,
                                                    int M, int N, int K) {
    __shared__ __align__(16) char lds[3][24576];  // per buf: A 8KB | B 16KB
    const int NKT = K >> 5;
    const int tid = threadIdx.x, wid = tid >> 6, lane = tid & 63;
    const int lr = lane & 15, lg = lane >> 4;
    const int nwg = gridDim.x, cpx = nwg >> 3;
    const int bid = blockIdx.x;
    const int swz = (bid & 7) * cpx + (bid >> 3);
    const int ntm = M >> 7;
    const int m0 = (swz % ntm) * 128, n0 = (swz / ntm) * 256;

    const int sc = (((tid & 3) ^ ((tid >> 3) & 3)) << 4);
    const int srow = tid >> 2;
    const char* pA0 = (const char*)A + ((size_t)(m0 + srow) * K) * 2 + sc;
    const char* pA1 = (const char*)A + ((size_t)(m0 + srow + 64) * K) * 2 + sc;
    const char* pB0 = (const char*)Bt + ((size_t)(n0 + srow) * K) * 2 + sc;
    const char* pB1 = (const char*)Bt + ((size_t)(n0 + srow + 64) * K) * 2 + sc;
    const char* pB2 = (const char*)Bt + ((size_t)(n0 + srow + 128) * K) * 2 + sc;
    const char* pB3 = (const char*)Bt + ((size_t)(n0 + srow + 192) * K) * 2 + sc;
    const int xoff = lr * 64 + ((lg ^ ((lr >> 1) & 3)) << 4);

    auto stage3a = [&](int kb, char* bp) {
        gload16(pA0 + kb, bp + tid * 16);
        gload16(pA1 + kb, bp + tid * 16 + 4096);
        gload16(pB0 + kb, bp + 8192 + tid * 16);
    };
    auto stage3b = [&](int kb, char* bp) {
        gload16(pB1 + kb, bp + 8192 + tid * 16 + 4096);
        gload16(pB2 + kb, bp + 8192 + tid * 16 + 8192);
        gload16(pB3 + kb, bp + 8192 + tid * 16 + 12288);
    };

    f32x4 acc[8][4];
#pragma unroll
    for (int m = 0; m < 8; ++m)
#pragma unroll
        for (int n = 0; n < 4; ++n) acc[m][n] = f32x4{0.f, 0.f, 0.f, 0.f};

    stage3a(0, lds[0]); stage3b(0, lds[0]);
    stage3a(64, lds[1]); stage3b(64, lds[1]);
    asm volatile("s_waitcnt vmcnt(6)" ::: "memory");
    __builtin_amdgcn_s_barrier();

    int cur = 0;
    for (int kt = 0; kt < NKT; ++kt) {
        const char* Al = lds[cur];
        const char* Bl = Al + 8192;
        int sb = cur + 2; if (sb >= 3) sb -= 3;
        char* sp = lds[sb];
        const bool st = (kt + 2) < NKT;
        const int kb = (kt + 2) << 6;

        bf16x8 bfr[4], afr[4];
#pragma unroll
        for (int n = 0; n < 4; ++n)
            bfr[n] = *(const bf16x8*)(Bl + wid * 4096 + n * 1024 + xoff);
#pragma unroll
        for (int m = 0; m < 4; ++m)
            afr[m] = *(const bf16x8*)(Al + m * 1024 + xoff);
        if (st) stage3a(kb, sp);
        __builtin_amdgcn_s_setprio(1);
#pragma unroll
        for (int m = 0; m < 4; ++m)
#pragma unroll
            for (int n = 0; n < 4; ++n)
                acc[m][n] = __builtin_amdgcn_mfma_f32_16x16x32_bf16(afr[m], bfr[n], acc[m][n], 0, 0, 0);
        __builtin_amdgcn_s_setprio(0);

#pragma unroll
        for (int m = 0; m < 4; ++m)
            afr[m] = *(const bf16x8*)(Al + (m + 4) * 1024 + xoff);
        if (st) stage3b(kb, sp);
        __builtin_amdgcn_s_setprio(1);
#pragma unroll
        for (int m = 0; m < 4; ++m)
#pragma unroll
            for (int n = 0; n < 4; ++n)
                acc[m + 4][n] = __builtin_amdgcn_mfma_f32_16x16x32_bf16(afr[m], bfr[n], acc[m + 4][n], 0, 0, 0);
        __builtin_amdgcn_s_setprio(0);

        if (kt < NKT - 1) {
            if (st) asm volatile("s_waitcnt vmcnt(6)" ::: "memory");
            else    asm volatile("s_waitcnt vmcnt(0)" ::: "memory");
            __builtin_amdgcn_s_barrier();
        }
        cur = cur + 1; if (cur >= 3) cur -= 3;
    }

    float bvals[4];
#pragma unroll
    for (int n = 0; n < 4; ++n) bvals[n] = bias[n0 + wid * 64 + n * 16 + lr];
#pragma unroll
    for (int m = 0; m < 8; ++m) {
        const size_t row = (size_t)(m0 + m * 16 + lg * 4);
#pragma unroll
        for (int n = 0; n < 4; ++n) {
            const int col = n0 + wid * 64 + n * 16 + lr;
#pragma unroll
            for (int i = 0; i < 4; ++i)
                C[(row + i) * N + col] = (OUTT)(acc[m][n][i] + bvals[n]);
        }
    }
}

// ---------------- 3-buffer pipelined GEMM: 128x128 tile (out-proj, grid 512) ----------------
__global__ __launch_bounds__(256, 2) void gemm_pipe_sq(const bf16_t* __restrict__ A,
                                                       const bf16_t* __restrict__ Bt,
                                                       const float* __restrict__ bias,
                                                       float* __restrict__ C,
                                                       int M, int N, int K) {
    __shared__ __align__(16) char lds[3][16384];  // per buf: A 8KB | B 8KB
    const int NKT = K >> 5;
    const int tid = threadIdx.x, wid = tid >> 6, lane = tid & 63;
    const int lr = lane & 15, lg = lane >> 4;
    const int wr = wid >> 1, wc = wid & 1;
    const int nwg = gridDim.x, cpx = nwg >> 3;
    const int bid = blockIdx.x;
    const int swz = (bid & 7) * cpx + (bid >> 3);
    const int ntm = M >> 7;
    const int m0 = (swz % ntm) * 128, n0 = (swz / ntm) * 128;

    const int sc = (((tid & 3) ^ ((tid >> 3) & 3)) << 4);
    const int srow = tid >> 2;
    const char* pA0 = (const char*)A + ((size_t)(m0 + srow) * K) * 2 + sc;
    const char* pA1 = (const char*)A + ((size_t)(m0 + srow + 64) * K) * 2 + sc;
    const char* pB0 = (const char*)Bt + ((size_t)(n0 + srow) * K) * 2 + sc;
    const char* pB1 = (const char*)Bt + ((size_t)(n0 + srow + 64) * K) * 2 + sc;
    const int xoff = lr * 64 + ((lg ^ ((lr >> 1) & 3)) << 4);

    auto stage4 = [&](int kb, char* bp) {
        gload16(pA0 + kb, bp + tid * 16);
        gload16(pA1 + kb, bp + tid * 16 + 4096);
        gload16(pB0 + kb, bp + 8192 + tid * 16);
        gload16(pB1 + kb, bp + 8192 + tid * 16 + 4096);
    };

    f32x4 acc[4][4];
#pragma unroll
    for (int m = 0; m < 4; ++m)
#pragma unroll
        for (int n = 0; n < 4; ++n) acc[m][n] = f32x4{0.f, 0.f, 0.f, 0.f};

    stage4(0, lds[0]);
    stage4(64, lds[1]);
    asm volatile("s_waitcnt vmcnt(4)" ::: "memory");
    __builtin_amdgcn_s_barrier();

    int cur = 0;
    for (int kt = 0; kt < NKT; ++kt) {
        const char* Al = lds[cur];
        const char* Bl = Al + 8192;
        int sb = cur + 2; if (sb >= 3) sb -= 3;
        char* sp = lds[sb];
        const bool st = (kt + 2) < NKT;

        bf16x8 bfr[4], afr[4];
#pragma unroll
        for (int n = 0; n < 4; ++n)
            bfr[n] = *(const bf16x8*)(Bl + wc * 4096 + n * 1024 + xoff);
#pragma unroll
        for (int m = 0; m < 4; ++m)
            afr[m] = *(const bf16x8*)(Al + wr * 4096 + m * 1024 + xoff);
        if (st) stage4((kt + 2) << 6, sp);
        __builtin_amdgcn_s_setprio(1);
#pragma unroll
        for (int m = 0; m < 4; ++m)
#pragma unroll
            for (int n = 0; n < 4; ++n)
                acc[m][n] = __builtin_amdgcn_mfma_f32_16x16x32_bf16(afr[m], bfr[n], acc[m][n], 0, 0, 0);
        __builtin_amdgcn_s_setprio(0);

        if (kt < NKT - 1) {
            if (st) asm volatile("s_waitcnt vmcnt(4)" ::: "memory");
            else    asm volatile("s_waitcnt vmcnt(0)" ::: "memory");
            __builtin_amdgcn_s_barrier();
        }
        cur = cur + 1; if (cur >= 3) cur -= 3;
    }

    float bvals[4];
#pragma unroll
    for (int n = 0; n < 4; ++n) bvals[n] = bias[n0 + wc * 64 + n * 16 + lr];
#pragma unroll
    for (int m = 0; m < 4; ++m) {
        const size_t row = (size_t)(m0 + wr * 64 + m * 16 + lg * 4);
#pragma unroll
        for (int n = 0; n < 4; ++n) {
            const int col = n0 + wc * 64 + n * 16 + lr;
#pragma unroll
            for (int i = 0; i < 4; ++i)
                C[(row + i) * N + col] = acc[m][n][i] + bvals[n];
        }
    }
}

// ---------------- cos/sin table: tab[n][j] = (cos, sin), 2048 x 64 ----------------
__global__ __launch_bounds__(256) void rope_cs(const int* __restrict__ Hp,
                                               const int* __restrict__ Wp,
                                               float2* __restrict__ tab) {
    const int idx = blockIdx.x * 256 + threadIdx.x;  // 512 blocks
    const int n = idx >> 6, j = idx & 63;
    const int Hh = *Hp, Ww = *Wp, HW = Hh * Ww;
    const int t = n / HW, rem = n % HW;
    const int hh = rem / Ww, w = rem % Ww;
    float pos = (j < 16) ? (float)t : (j < 40 ? (float)hh : (float)w);
    float inv = expf(-(float)j * (9.210340371976184f / 64.f));
    float ang = pos * inv;
    tab[idx] = make_float2(cosf(ang), sinf(ang));
}

// ---------------- fused MRoPE (q,k) + v transpose (table-driven) ----------------
__global__ __launch_bounds__(256) void rope_fused(const bf16_t* __restrict__ qkv,
                                                  bf16_t* __restrict__ qT,
                                                  bf16_t* __restrict__ kT,
                                                  bf16_t* __restrict__ vT,
                                                  const float2* __restrict__ tab) {
    const int blk = blockIdx.x;          // 1024 = 32 bh x 32 token-tiles
    const int bh = blk >> 5;
    const int n0 = (blk & 31) * 64;
    const int b = bh >> 4, h = bh & 15;
    const int tid = threadIdx.x;
    __shared__ bf16_t vt[64][132];       // [tok][d], +4 pad

    const float qscale = 0.08838834764831845f;  // 1/sqrt(128)
    const int jg = tid & 7, tn = tid >> 3;      // 32 tokens per pass
#pragma unroll
    for (int p = 0; p < 2; ++p) {
        const int tok = p * 32 + tn, n = n0 + tok;
        const bf16_t* base = qkv + (size_t)(b * NTOK + n) * QKVCOLS + h * HD + jg * 8;
        bf16x8 q1 = *(const bf16x8*)(base);
        bf16x8 q2 = *(const bf16x8*)(base + 64);
        bf16x8 k1 = *(const bf16x8*)(base + 2048);
        bf16x8 k2 = *(const bf16x8*)(base + 2048 + 64);
        bf16x8 v1 = *(const bf16x8*)(base + 4096);
        bf16x8 v2 = *(const bf16x8*)(base + 4096 + 64);
        union { float4 f4[4]; float2 f2[8]; } cs;
        const float4* cp4 = (const float4*)(tab + (size_t)n * 64 + jg * 8);
#pragma unroll
        for (int i = 0; i < 4; ++i) cs.f4[i] = cp4[i];
        bf16x8 oq1, oq2, ok1, ok2;
#pragma unroll
        for (int i = 0; i < 8; ++i) {
            float c = cs.f2[i].x, s = cs.f2[i].y;
            float a = (float)q1[i], bb = (float)q2[i];
            oq1[i] = (bf16_t)((a * c - bb * s) * qscale);
            oq2[i] = (bf16_t)((bb * c + a * s) * qscale);
            a = (float)k1[i]; bb = (float)k2[i];
            ok1[i] = (bf16_t)(a * c - bb * s);
            ok2[i] = (bf16_t)(bb * c + a * s);
        }
        const size_t qo = ((size_t)bh * NTOK + n) * HD + jg * 8;
        *(bf16x8*)(qT + qo) = oq1;
        *(bf16x8*)(qT + qo + 64) = oq2;
        *(bf16x8*)(kT + qo) = ok1;
        *(bf16x8*)(kT + qo + 64) = ok2;
        *(bf16x8*)&vt[tok][jg * 8] = v1;
        *(bf16x8*)&vt[tok][jg * 8 + 64] = v2;
    }
    __syncthreads();

    // vT[bh][d][NTOK]: thread (d = tid>>1, half = tid&1) writes 32 tokens
    const int d = tid >> 1, th = (tid & 1) * 32;
    bf16_t* orow = vT + ((size_t)bh * HD + d) * NTOK + n0 + th;
#pragma unroll
    for (int c = 0; c < 4; ++c) {
        bf16x8 tmp;
#pragma unroll
        for (int e = 0; e < 8; ++e) tmp[e] = vt[th + c * 8 + e][d];
        *(bf16x8*)(orow + c * 8) = tmp;
    }
}

// ---------------- flash attention: 4 waves x 32 q-rows, 32x32 MFMA ----------------
__global__ __launch_bounds__(256, 2) void attn_kernel(const bf16_t* __restrict__ qT,
                                                      const bf16_t* __restrict__ kT,
                                                      const bf16_t* __restrict__ vT,
                                                      bf16_t* __restrict__ outp) {
    __shared__ __align__(16) char lds[2][32768];  // per buf: K tile 16KB | V tile 16KB
    const int B = blockIdx.x;
    const int xcd = B & 7, jj = B >> 3;
    const int bh = xcd * 4 + (jj >> 4);
    const int q0 = (jj & 15) * 128;
    const int tid = threadIdx.x, wid = tid >> 6, lane = tid & 63;
    const int ql = lane & 31, hi = lane >> 5;

    const bf16_t* Q = qT + (size_t)bh * NTOK * HD;
    const char* Kb = (const char*)(kT + (size_t)bh * NTOK * HD);
    const char* Vb = (const char*)(vT + (size_t)bh * NTOK * HD);

    bf16x8 qf[8];
    {
        const bf16_t* qrow = Q + (size_t)(q0 + wid * 32 + ql) * HD + hi * 8;
#pragma unroll
        for (int kc = 0; kc < 8; ++kc) qf[kc] = *(const bf16x8*)(qrow + kc * 16);
    }
    f32x16 oa[4];
#pragma unroll
    for (int df = 0; df < 4; ++df)
#pragma unroll
        for (int r = 0; r < 16; ++r) oa[df][r] = 0.f;
    float m_run = -1e30f, l_run = 0.f;
    const float L2E = 1.44269504089f;

    auto stage = [&](int t, int buf) {
#pragma unroll
        for (int i = 0; i < 4; ++i) {
            int a = wid * 4096 + i * 1024 + lane * 16;
            int row = a >> 8;
            int col = (a & 255) ^ ((row & 7) << 4);
            gload16(Kb + (size_t)(t * 64 + row) * 256 + col,
                    (char*)lds[buf] + wid * 4096 + i * 1024);
        }
#pragma unroll
        for (int i = 0; i < 4; ++i) {
            int a = wid * 4096 + i * 1024 + lane * 16;
            int row = a >> 7;
            int col = (a & 127) ^ ((row & 7) << 4);
            gload16(Vb + (size_t)row * (NTOK * 2) + t * 128 + col,
                    (char*)lds[buf] + 16384 + wid * 4096 + i * 1024);
        }
    };
    stage(0, 0);
    __syncthreads();

    for (int t = 0; t < NTOK / 64; ++t) {
        if (t < NTOK / 64 - 1) stage(t + 1, (t + 1) & 1);
        const char* Kl = lds[t & 1];
        const char* Vl = Kl + 16384;

        f32x16 s[2];
#pragma unroll
        for (int nb = 0; nb < 2; ++nb) {
#pragma unroll
            for (int r = 0; r < 16; ++r) s[nb][r] = 0.f;
            int row = nb * 32 + ql;
            const char* krow = Kl + row * 256;
            int sw = (row & 7) << 4;
            __builtin_amdgcn_s_setprio(1);
#pragma unroll
            for (int kc = 0; kc < 8; ++kc) {
                bf16x8 kf = *(const bf16x8*)(krow + ((kc * 32 + hi * 16) ^ sw));
                s[nb] = __builtin_amdgcn_mfma_f32_32x32x16_bf16(kf, qf[kc], s[nb], 0, 0, 0);
            }
            __builtin_amdgcn_s_setprio(0);
        }

        // ---- tree max ----
        float t16[16];
#pragma unroll
        for (int r = 0; r < 16; ++r) t16[r] = fmaxf(s[0][r], s[1][r]);
#pragma unroll
        for (int st = 8; st >= 1; st >>= 1)
#pragma unroll
            for (int r = 0; r < st; ++r) t16[r] = fmaxf(t16[r], t16[r + st]);
        float mx = fmaxf(t16[0], __shfl_xor(t16[0], 32));
        if (__any(mx - m_run > 8.f)) {
            float mn = fmaxf(m_run, mx);
            float resc = __expf(m_run - mn);
            l_run *= resc;
#pragma unroll
            for (int df = 0; df < 4; ++df) oa[df] *= resc;
            m_run = mn;
        }
        // ---- exp2-fused P, tree sum ----
        const float mb = m_run * L2E;
#pragma unroll
        for (int nb = 0; nb < 2; ++nb)
#pragma unroll
            for (int r = 0; r < 16; ++r)
                s[nb][r] = exp2f(fmaf(s[nb][r], L2E, -mb));
        float u16[16];
#pragma unroll
        for (int r = 0; r < 16; ++r) u16[r] = s[0][r] + s[1][r];
#pragma unroll
        for (int st = 8; st >= 1; st >>= 1)
#pragma unroll
            for (int r = 0; r < st; ++r) u16[r] += u16[r + st];
        float rs = u16[0] + __shfl_xor(u16[0], 32);
        l_run += rs;

        unsigned int pk[2][8];
#pragma unroll
        for (int nb = 0; nb < 2; ++nb)
#pragma unroll
            for (int m = 0; m < 8; ++m) pk[nb][m] = pack2bf(s[nb][2 * m], s[nb][2 * m + 1]);

        // ---- PV: P redistribution via permlane32_swap (T12) ----
#pragma unroll
        for (int kc2 = 0; kc2 < 4; ++kc2) {
            const int nb = kc2 >> 1, c1 = kc2 & 1;
            unsigned int a0 = pk[nb][4 * c1 + 0], b0 = pk[nb][4 * c1 + 2];
            unsigned int a1 = pk[nb][4 * c1 + 1], b1 = pk[nb][4 * c1 + 3];
            // a' = {a.lo, b.lo}, b' = {a.hi, b.hi} (lane-halves)
            asm("v_permlane32_swap_b32 %0, %1" : "+v"(a0), "+v"(b0));
            asm("v_permlane32_swap_b32 %0, %1" : "+v"(a1), "+v"(b1));
            union { unsigned int u[4]; bf16x8 v; } pb;
            pb.u[0] = a0; pb.u[1] = a1; pb.u[2] = b0; pb.u[3] = b1;
            __builtin_amdgcn_s_setprio(1);
#pragma unroll
            for (int df = 0; df < 4; ++df) {
                int row = df * 32 + ql;
                bf16x8 va = *(const bf16x8*)(Vl + row * 128 + ((kc2 * 32 + hi * 16) ^ ((row & 7) << 4)));
                oa[df] = __builtin_amdgcn_mfma_f32_32x32x16_bf16(va, pb.v, oa[df], 0, 0, 0);
            }
            __builtin_amdgcn_s_setprio(0);
        }
        __syncthreads();
    }

    float inv = 1.f / l_run;
    bf16_t* Ot = (bf16_t*)((char*)lds + wid * 8704);
#pragma unroll
    for (int df = 0; df < 4; ++df)
#pragma unroll
        for (int rg = 0; rg < 4; ++rg) {
            bf16x4 w;
#pragma unroll
            for (int i = 0; i < 4; ++i) w[i] = (bf16_t)(oa[df][rg * 4 + i] * inv);
            int d0 = df * 32 + rg * 8 + hi * 4;
            *(bf16x4*)&Ot[ql * 136 + d0] = w;
        }
    __builtin_amdgcn_s_waitcnt(0);
    const int qloc = lane >> 1, half = lane & 1;
    const int b = bh >> 4, h = bh & 15;
    bf16_t* orow = outp + (size_t)(b * NTOK + q0 + wid * 32 + qloc) * HIDDEN + h * HD + half * 64;
    const bf16_t* src = Ot + qloc * 136 + half * 64;
#pragma unroll
    for (int c = 0; c < 8; ++c)
        *(bf16x8*)(orow + c * 8) = *(const bf16x8*)(src + c * 8);
}

extern "C" void kernel_launch(void* const* d_in, const int* in_sizes, int n_in,
                              void* d_out, int out_size, void* d_ws, size_t ws_size,
                              hipStream_t stream) {
    const float* x = (const float*)d_in[0];
    const float* w_qkv = (const float*)d_in[1];
    const float* b_qkv = (const float*)d_in[2];
    const float* w_proj = (const float*)d_in[3];
    const float* b_proj = (const float*)d_in[4];
    const int* Hp = (const int*)d_in[6];
    const int* Wp = (const int*)d_in[7];
    float* out = (float*)d_out;

    char* ws = (char*)d_ws;
    bf16_t* xb = (bf16_t*)(ws + 0);                       // 16 MiB  [4096][2048]
    bf16_t* wqkvT = (bf16_t*)(ws + 16777216);             // 24 MiB  [6144][2048]
    bf16_t* wprojT = (bf16_t*)(ws + 41943040);            // 8 MiB   [2048][2048]
    bf16_t* qkv = (bf16_t*)(ws + 50331648);               // 48 MiB  [4096][6144]
    bf16_t* qTb = (bf16_t*)(ws + 100663296);              // 16 MiB  [32][2048][128]
    bf16_t* kTb = (bf16_t*)(ws + 117440512);              // 16 MiB
    float2* tab = (float2*)(ws + 0);                      // 1 MiB, reuse xb after gemm1
    bf16_t* vT = (bf16_t*)(ws + 16777216);                // reuse wqkvT region after gemm1
    bf16_t* attno = (bf16_t*)(ws + 50331648);             // reuse qkv region after rope

    cvt8_kernel<<<4096, 256, 0, stream>>>(x, xb, 1048576);
    cvtT_kernel<<<dim3(96, 32), 256, 0, stream>>>(w_qkv, wqkvT, 2048, 6144);
    cvtT_kernel<<<dim3(32, 32), 256, 0, stream>>>(w_proj, wprojT, 2048, 2048);
    gemm_pipe<bf16_t><<<768, 256, 0, stream>>>(xb, wqkvT, b_qkv, qkv, MROWS, QKVCOLS, HIDDEN);
    rope_cs<<<512, 256, 0, stream>>>(Hp, Wp, tab);
    rope_fused<<<1024, 256, 0, stream>>>(qkv, qTb, kTb, vT, tab);
    attn_kernel<<<512, 256, 0, stream>>>(qTb, kTb, vT, attno);
    gemm_pipe_sq<<<512, 256, 0, stream>>>(attno, wprojT, b_proj, out, MROWS, HIDDEN, HIDDEN);
}

// Round 8
// 289.519 us; speedup vs baseline: 1.0354x; 1.0150x over previous
//
#include <hip/hip_runtime.h>
#include <hip/hip_bf16.h>

typedef __bf16 bf16_t;
typedef __bf16 bf16x8 __attribute__((ext_vector_type(8)));
typedef __bf16 bf16x4 __attribute__((ext_vector_type(4)));
typedef float f32x4 __attribute__((ext_vector_type(4)));
typedef float f32x16 __attribute__((ext_vector_type(16)));

#define HIDDEN 2048
#define NHEADS 16
#define HD 128
#define NTOK 2048
#define BATCH 2
#define MROWS (BATCH*NTOK)
#define QKVCOLS (3*HIDDEN)

__device__ __forceinline__ void gload16(const void* g, void* l) {
    __builtin_amdgcn_global_load_lds(
        (const __attribute__((address_space(1))) void*)g,
        (__attribute__((address_space(3))) void*)l,
        16, 0, 0);
}

__device__ __forceinline__ unsigned int pack2bf(float lo, float hi2) {
    union { bf16_t h[2]; unsigned int u; } t;
    t.h[0] = (bf16_t)lo; t.h[1] = (bf16_t)hi2;
    return t.u;
}

// ---------------- fp32 -> bf16 elementwise (x) ----------------
__global__ __launch_bounds__(256) void cvt8_kernel(const float* __restrict__ in,
                                                   bf16_t* __restrict__ out, int n8) {
    int i = blockIdx.x * blockDim.x + threadIdx.x;
    if (i >= n8) return;
    const float4 a = *(const float4*)(in + (size_t)i * 8);
    const float4 b = *(const float4*)(in + (size_t)i * 8 + 4);
    bf16x8 r;
    r[0] = (bf16_t)a.x; r[1] = (bf16_t)a.y; r[2] = (bf16_t)a.z; r[3] = (bf16_t)a.w;
    r[4] = (bf16_t)b.x; r[5] = (bf16_t)b.y; r[6] = (bf16_t)b.z; r[7] = (bf16_t)b.w;
    *(bf16x8*)(out + (size_t)i * 8) = r;
}

// ---------------- fp32 KxN -> bf16 NxK transpose-convert ----------------
__global__ __launch_bounds__(256) void cvtT_kernel(const float* __restrict__ in,
                                                   bf16_t* __restrict__ out, int K, int N) {
    __shared__ float t[64][65];
    const int n0 = blockIdx.x * 64, k0 = blockIdx.y * 64;
    const int tid = threadIdx.x, c = tid & 63, r4 = tid >> 6;
#pragma unroll
    for (int rr = 0; rr < 64; rr += 4)
        t[rr + r4][c] = in[(size_t)(k0 + rr + r4) * N + n0 + c];
    __syncthreads();
#pragma unroll
    for (int rr = 0; rr < 64; rr += 4) {
        int nn = rr + r4;
        out[(size_t)(n0 + nn) * K + k0 + c] = (bf16_t)t[c][nn];
    }
}

// ---------------- 3-buffer pipelined GEMM: 128x256 tile (QKV proj) ----------------
template <typename OUTT>
__global__ __launch_bounds__(256, 2) void gemm_pipe(const bf16_t* __restrict__ A,
                                                    const bf16_t* __restrict__ Bt,
                                                    const float* __restrict__ bias,
                                                    OUTT* __restrict__ C,
                                                    int M, int N, int K) {
    __shared__ __align__(16) char lds[3][24576];  // per buf: A 8KB | B 16KB
    const int NKT = K >> 5;
    const int tid = threadIdx.x, wid = tid >> 6, lane = tid & 63;
    const int lr = lane & 15, lg = lane >> 4;
    const int nwg = gridDim.x, cpx = nwg >> 3;
    const int bid = blockIdx.x;
    const int swz = (bid & 7) * cpx + (bid >> 3);
    const int ntm = M >> 7;
    const int m0 = (swz % ntm) * 128, n0 = (swz / ntm) * 256;

    const int sc = (((tid & 3) ^ ((tid >> 3) & 3)) << 4);
    const int srow = tid >> 2;
    const char* pA0 = (const char*)A + ((size_t)(m0 + srow) * K) * 2 + sc;
    const char* pA1 = (const char*)A + ((size_t)(m0 + srow + 64) * K) * 2 + sc;
    const char* pB0 = (const char*)Bt + ((size_t)(n0 + srow) * K) * 2 + sc;
    const char* pB1 = (const char*)Bt + ((size_t)(n0 + srow + 64) * K) * 2 + sc;
    const char* pB2 = (const char*)Bt + ((size_t)(n0 + srow + 128) * K) * 2 + sc;
    const char* pB3 = (const char*)Bt + ((size_t)(n0 + srow + 192) * K) * 2 + sc;
    const int xoff = lr * 64 + ((lg ^ ((lr >> 1) & 3)) << 4);

    auto stage3a = [&](int kb, char* bp) {
        gload16(pA0 + kb, bp + tid * 16);
        gload16(pA1 + kb, bp + tid * 16 + 4096);
        gload16(pB0 + kb, bp + 8192 + tid * 16);
    };
    auto stage3b = [&](int kb, char* bp) {
        gload16(pB1 + kb, bp + 8192 + tid * 16 + 4096);
        gload16(pB2 + kb, bp + 8192 + tid * 16 + 8192);
        gload16(pB3 + kb, bp + 8192 + tid * 16 + 12288);
    };

    f32x4 acc[8][4];
#pragma unroll
    for (int m = 0; m < 8; ++m)
#pragma unroll
        for (int n = 0; n < 4; ++n) acc[m][n] = f32x4{0.f, 0.f, 0.f, 0.f};

    stage3a(0, lds[0]); stage3b(0, lds[0]);
    stage3a(64, lds[1]); stage3b(64, lds[1]);
    asm volatile("s_waitcnt vmcnt(6)" ::: "memory");
    __builtin_amdgcn_s_barrier();

    int cur = 0;
    for (int kt = 0; kt < NKT; ++kt) {
        const char* Al = lds[cur];
        const char* Bl = Al + 8192;
        int sb = cur + 2; if (sb >= 3) sb -= 3;
        char* sp = lds[sb];
        const bool st = (kt + 2) < NKT;
        const int kb = (kt + 2) << 6;

        bf16x8 bfr[4], afr[4];
#pragma unroll
        for (int n = 0; n < 4; ++n)
            bfr[n] = *(const bf16x8*)(Bl + wid * 4096 + n * 1024 + xoff);
#pragma unroll
        for (int m = 0; m < 4; ++m)
            afr[m] = *(const bf16x8*)(Al + m * 1024 + xoff);
        if (st) stage3a(kb, sp);
        __builtin_amdgcn_s_setprio(1);
#pragma unroll
        for (int m = 0; m < 4; ++m)
#pragma unroll
            for (int n = 0; n < 4; ++n)
                acc[m][n] = __builtin_amdgcn_mfma_f32_16x16x32_bf16(afr[m], bfr[n], acc[m][n], 0, 0, 0);
        __builtin_amdgcn_s_setprio(0);

#pragma unroll
        for (int m = 0; m < 4; ++m)
            afr[m] = *(const bf16x8*)(Al + (m + 4) * 1024 + xoff);
        if (st) stage3b(kb, sp);
        __builtin_amdgcn_s_setprio(1);
#pragma unroll
        for (int m = 0; m < 4; ++m)
#pragma unroll
            for (int n = 0; n < 4; ++n)
                acc[m + 4][n] = __builtin_amdgcn_mfma_f32_16x16x32_bf16(afr[m], bfr[n], acc[m + 4][n], 0, 0, 0);
        __builtin_amdgcn_s_setprio(0);

        if (kt < NKT - 1) {
            if (st) asm volatile("s_waitcnt vmcnt(6)" ::: "memory");
            else    asm volatile("s_waitcnt vmcnt(0)" ::: "memory");
            __builtin_amdgcn_s_barrier();
        }
        cur = cur + 1; if (cur >= 3) cur -= 3;
    }

    float bvals[4];
#pragma unroll
    for (int n = 0; n < 4; ++n) bvals[n] = bias[n0 + wid * 64 + n * 16 + lr];
#pragma unroll
    for (int m = 0; m < 8; ++m) {
        const size_t row = (size_t)(m0 + m * 16 + lg * 4);
#pragma unroll
        for (int n = 0; n < 4; ++n) {
            const int col = n0 + wid * 64 + n * 16 + lr;
#pragma unroll
            for (int i = 0; i < 4; ++i)
                C[(row + i) * N + col] = (OUTT)(acc[m][n][i] + bvals[n]);
        }
    }
}

// ---------------- 3-buffer pipelined GEMM: 128x128 tile (out-proj, grid 512) ----------------
__global__ __launch_bounds__(256, 2) void gemm_pipe_sq(const bf16_t* __restrict__ A,
                                                       const bf16_t* __restrict__ Bt,
                                                       const float* __restrict__ bias,
                                                       float* __restrict__ C,
                                                       int M, int N, int K) {
    __shared__ __align__(16) char lds[3][16384];  // per buf: A 8KB | B 8KB
    const int NKT = K >> 5;
    const int tid = threadIdx.x, wid = tid >> 6, lane = tid & 63;
    const int lr = lane & 15, lg = lane >> 4;
    const int wr = wid >> 1, wc = wid & 1;
    const int nwg = gridDim.x, cpx = nwg >> 3;
    const int bid = blockIdx.x;
    const int swz = (bid & 7) * cpx + (bid >> 3);
    const int ntm = M >> 7;
    const int m0 = (swz % ntm) * 128, n0 = (swz / ntm) * 128;

    const int sc = (((tid & 3) ^ ((tid >> 3) & 3)) << 4);
    const int srow = tid >> 2;
    const char* pA0 = (const char*)A + ((size_t)(m0 + srow) * K) * 2 + sc;
    const char* pA1 = (const char*)A + ((size_t)(m0 + srow + 64) * K) * 2 + sc;
    const char* pB0 = (const char*)Bt + ((size_t)(n0 + srow) * K) * 2 + sc;
    const char* pB1 = (const char*)Bt + ((size_t)(n0 + srow + 64) * K) * 2 + sc;
    const int xoff = lr * 64 + ((lg ^ ((lr >> 1) & 3)) << 4);

    auto stage4 = [&](int kb, char* bp) {
        gload16(pA0 + kb, bp + tid * 16);
        gload16(pA1 + kb, bp + tid * 16 + 4096);
        gload16(pB0 + kb, bp + 8192 + tid * 16);
        gload16(pB1 + kb, bp + 8192 + tid * 16 + 4096);
    };

    f32x4 acc[4][4];
#pragma unroll
    for (int m = 0; m < 4; ++m)
#pragma unroll
        for (int n = 0; n < 4; ++n) acc[m][n] = f32x4{0.f, 0.f, 0.f, 0.f};

    stage4(0, lds[0]);
    stage4(64, lds[1]);
    asm volatile("s_waitcnt vmcnt(4)" ::: "memory");
    __builtin_amdgcn_s_barrier();

    int cur = 0;
    for (int kt = 0; kt < NKT; ++kt) {
        const char* Al = lds[cur];
        const char* Bl = Al + 8192;
        int sb = cur + 2; if (sb >= 3) sb -= 3;
        char* sp = lds[sb];
        const bool st = (kt + 2) < NKT;

        bf16x8 bfr[4], afr[4];
#pragma unroll
        for (int n = 0; n < 4; ++n)
            bfr[n] = *(const bf16x8*)(Bl + wc * 4096 + n * 1024 + xoff);
#pragma unroll
        for (int m = 0; m < 4; ++m)
            afr[m] = *(const bf16x8*)(Al + wr * 4096 + m * 1024 + xoff);
        if (st) stage4((kt + 2) << 6, sp);
        __builtin_amdgcn_s_setprio(1);
#pragma unroll
        for (int m = 0; m < 4; ++m)
#pragma unroll
            for (int n = 0; n < 4; ++n)
                acc[m][n] = __builtin_amdgcn_mfma_f32_16x16x32_bf16(afr[m], bfr[n], acc[m][n], 0, 0, 0);
        __builtin_amdgcn_s_setprio(0);

        if (kt < NKT - 1) {
            if (st) asm volatile("s_waitcnt vmcnt(4)" ::: "memory");
            else    asm volatile("s_waitcnt vmcnt(0)" ::: "memory");
            __builtin_amdgcn_s_barrier();
        }
        cur = cur + 1; if (cur >= 3) cur -= 3;
    }

    float bvals[4];
#pragma unroll
    for (int n = 0; n < 4; ++n) bvals[n] = bias[n0 + wc * 64 + n * 16 + lr];
#pragma unroll
    for (int m = 0; m < 4; ++m) {
        const size_t row = (size_t)(m0 + wr * 64 + m * 16 + lg * 4);
#pragma unroll
        for (int n = 0; n < 4; ++n) {
            const int col = n0 + wc * 64 + n * 16 + lr;
#pragma unroll
            for (int i = 0; i < 4; ++i)
                C[(row + i) * N + col] = acc[m][n][i] + bvals[n];
        }
    }
}

// ---------------- cos/sin table: tab[n][j] = (cos, sin), 2048 x 64 ----------------
__global__ __launch_bounds__(256) void rope_cs(const int* __restrict__ Hp,
                                               const int* __restrict__ Wp,
                                               float2* __restrict__ tab) {
    const int idx = blockIdx.x * 256 + threadIdx.x;  // 512 blocks
    const int n = idx >> 6, j = idx & 63;
    const int Hh = *Hp, Ww = *Wp, HW = Hh * Ww;
    const int t = n / HW, rem = n % HW;
    const int hh = rem / Ww, w = rem % Ww;
    float pos = (j < 16) ? (float)t : (j < 40 ? (float)hh : (float)w);
    float inv = expf(-(float)j * (9.210340371976184f / 64.f));
    float ang = pos * inv;
    tab[idx] = make_float2(cosf(ang), sinf(ang));
}

// ---------------- fused MRoPE (q,k) + v transpose (table-driven) ----------------
__global__ __launch_bounds__(256) void rope_fused(const bf16_t* __restrict__ qkv,
                                                  bf16_t* __restrict__ qT,
                                                  bf16_t* __restrict__ kT,
                                                  bf16_t* __restrict__ vT,
                                                  const float2* __restrict__ tab) {
    const int blk = blockIdx.x;          // 1024 = 32 bh x 32 token-tiles
    const int bh = blk >> 5;
    const int n0 = (blk & 31) * 64;
    const int b = bh >> 4, h = bh & 15;
    const int tid = threadIdx.x;
    __shared__ bf16_t vt[64][132];       // [tok][d], +4 pad

    const float qscale = 0.08838834764831845f;  // 1/sqrt(128)
    const int jg = tid & 7, tn = tid >> 3;      // 32 tokens per pass
#pragma unroll
    for (int p = 0; p < 2; ++p) {
        const int tok = p * 32 + tn, n = n0 + tok;
        const bf16_t* base = qkv + (size_t)(b * NTOK + n) * QKVCOLS + h * HD + jg * 8;
        bf16x8 q1 = *(const bf16x8*)(base);
        bf16x8 q2 = *(const bf16x8*)(base + 64);
        bf16x8 k1 = *(const bf16x8*)(base + 2048);
        bf16x8 k2 = *(const bf16x8*)(base + 2048 + 64);
        bf16x8 v1 = *(const bf16x8*)(base + 4096);
        bf16x8 v2 = *(const bf16x8*)(base + 4096 + 64);
        union { float4 f4[4]; float2 f2[8]; } cs;
        const float4* cp4 = (const float4*)(tab + (size_t)n * 64 + jg * 8);
#pragma unroll
        for (int i = 0; i < 4; ++i) cs.f4[i] = cp4[i];
        bf16x8 oq1, oq2, ok1, ok2;
#pragma unroll
        for (int i = 0; i < 8; ++i) {
            float c = cs.f2[i].x, s = cs.f2[i].y;
            float a = (float)q1[i], bb = (float)q2[i];
            oq1[i] = (bf16_t)((a * c - bb * s) * qscale);
            oq2[i] = (bf16_t)((bb * c + a * s) * qscale);
            a = (float)k1[i]; bb = (float)k2[i];
            ok1[i] = (bf16_t)(a * c - bb * s);
            ok2[i] = (bf16_t)(bb * c + a * s);
        }
        const size_t qo = ((size_t)bh * NTOK + n) * HD + jg * 8;
        *(bf16x8*)(qT + qo) = oq1;
        *(bf16x8*)(qT + qo + 64) = oq2;
        *(bf16x8*)(kT + qo) = ok1;
        *(bf16x8*)(kT + qo + 64) = ok2;
        *(bf16x8*)&vt[tok][jg * 8] = v1;
        *(bf16x8*)&vt[tok][jg * 8 + 64] = v2;
    }
    __syncthreads();

    // vT[bh][d][NTOK]: thread (d = tid>>1, half = tid&1) writes 32 tokens
    const int d = tid >> 1, th = (tid & 1) * 32;
    bf16_t* orow = vT + ((size_t)bh * HD + d) * NTOK + n0 + th;
#pragma unroll
    for (int c = 0; c < 4; ++c) {
        bf16x8 tmp;
#pragma unroll
        for (int e = 0; e < 8; ++e) tmp[e] = vt[th + c * 8 + e][d];
        *(bf16x8*)(orow + c * 8) = tmp;
    }
}

// ---------------- flash attention v3: no setprio, hoisted addrs, split-nb overlap ----------------
__global__ __launch_bounds__(256, 2) void attn_kernel(const bf16_t* __restrict__ qT,
                                                      const bf16_t* __restrict__ kT,
                                                      const bf16_t* __restrict__ vT,
                                                      bf16_t* __restrict__ outp) {
    __shared__ __align__(16) char lds[2][32768];  // per buf: K tile 16KB | V tile 16KB
    const int B = blockIdx.x;
    const int xcd = B & 7, jj = B >> 3;
    const int bh = xcd * 4 + (jj >> 4);
    const int q0 = (jj & 15) * 128;
    const int tid = threadIdx.x, wid = tid >> 6, lane = tid & 63;
    const int ql = lane & 31, hi = lane >> 5;

    const bf16_t* Q = qT + (size_t)bh * NTOK * HD;
    const char* Kb = (const char*)(kT + (size_t)bh * NTOK * HD);
    const char* Vb = (const char*)(vT + (size_t)bh * NTOK * HD);

    bf16x8 qf[8];
    {
        const bf16_t* qrow = Q + (size_t)(q0 + wid * 32 + ql) * HD + hi * 8;
#pragma unroll
        for (int kc = 0; kc < 8; ++kc) qf[kc] = *(const bf16x8*)(qrow + kc * 16);
    }
    f32x16 oa[4];
#pragma unroll
    for (int df = 0; df < 4; ++df)
#pragma unroll
        for (int r = 0; r < 16; ++r) oa[df][r] = 0.f;
    float m_run = -1e30f, l_run = 0.f;
    const float L2E = 1.44269504089f;

    // ---- hoisted LDS read offsets ----
    const int sw = (ql & 7) << 4;
    int xk[8];
#pragma unroll
    for (int kc = 0; kc < 8; ++kc) xk[kc] = (kc * 32 + hi * 16) ^ sw;
    const int krb0 = ql * 256, krb1 = (32 + ql) * 256;
    int vrb[4];
#pragma unroll
    for (int df = 0; df < 4; ++df) vrb[df] = 16384 + (df * 32 + ql) * 128;

    // ---- hoisted staging pointers (advance by constant per tile) ----
    const char* kgp[4];
    const char* vgp[4];
    const int ldso[4] = {wid * 4096, wid * 4096 + 1024, wid * 4096 + 2048, wid * 4096 + 3072};
#pragma unroll
    for (int i = 0; i < 4; ++i) {
        int a = wid * 4096 + i * 1024 + lane * 16;
        int row = a >> 8;
        int col = (a & 255) ^ ((row & 7) << 4);
        kgp[i] = Kb + (size_t)row * 256 + col;
        int row2 = a >> 7;
        int col2 = (a & 127) ^ ((row2 & 7) << 4);
        vgp[i] = Vb + (size_t)row2 * (NTOK * 2) + col2;
    }

    // prologue: stage tile 0 into buf 0
#pragma unroll
    for (int i = 0; i < 4; ++i) gload16(kgp[i], lds[0] + ldso[i]);
#pragma unroll
    for (int i = 0; i < 4; ++i) gload16(vgp[i], lds[0] + 16384 + ldso[i]);
    __syncthreads();

#pragma unroll 2
    for (int t = 0; t < NTOK / 64; ++t) {
        const int buf = t & 1;
        if (t < NTOK / 64 - 1) {
            const size_t ko = (size_t)(t + 1) * 16384;
            const size_t vo = (size_t)(t + 1) * 128;
            char* db = lds[buf ^ 1];
#pragma unroll
            for (int i = 0; i < 4; ++i) gload16(kgp[i] + ko, db + ldso[i]);
#pragma unroll
            for (int i = 0; i < 4; ++i) gload16(vgp[i] + vo, db + 16384 + ldso[i]);
        }
        const char* Kl = lds[buf];

        // ---- QK^T both halves ----
        f32x16 s0, s1;
#pragma unroll
        for (int r = 0; r < 16; ++r) { s0[r] = 0.f; s1[r] = 0.f; }
#pragma unroll
        for (int kc = 0; kc < 8; ++kc) {
            bf16x8 kf0 = *(const bf16x8*)(Kl + krb0 + xk[kc]);
            s0 = __builtin_amdgcn_mfma_f32_32x32x16_bf16(kf0, qf[kc], s0, 0, 0, 0);
        }
#pragma unroll
        for (int kc = 0; kc < 8; ++kc) {
            bf16x8 kf1 = *(const bf16x8*)(Kl + krb1 + xk[kc]);
            s1 = __builtin_amdgcn_mfma_f32_32x32x16_bf16(kf1, qf[kc], s1, 0, 0, 0);
        }

        // ---- max trees + merge ----
        float t16[16];
#pragma unroll
        for (int r = 0; r < 16; ++r) t16[r] = fmaxf(s0[r], s1[r]);
#pragma unroll
        for (int st = 8; st >= 1; st >>= 1)
#pragma unroll
            for (int r = 0; r < st; ++r) t16[r] = fmaxf(t16[r], t16[r + st]);
        float mx = fmaxf(t16[0], __shfl_xor(t16[0], 32));
        if (__any(mx - m_run > 8.f)) {
            float mn = fmaxf(m_run, mx);
            float resc = __expf(m_run - mn);
            l_run *= resc;
#pragma unroll
            for (int df = 0; df < 4; ++df) oa[df] *= resc;
            m_run = mn;
        }
        const float mb = m_run * L2E;

        // ---- half 0: exp + pack, then PV kc2=0,1 (dataflow allows overlap) ----
        float sum0 = 0.f, sum1 = 0.f;
#pragma unroll
        for (int r = 0; r < 16; ++r) s0[r] = exp2f(fmaf(s0[r], L2E, -mb));
        unsigned int pk0[8];
#pragma unroll
        for (int m = 0; m < 8; ++m) pk0[m] = pack2bf(s0[2 * m], s0[2 * m + 1]);
        {
            float u[8];
#pragma unroll
            for (int r = 0; r < 8; ++r) u[r] = s0[r] + s0[r + 8];
#pragma unroll
            for (int st = 4; st >= 1; st >>= 1)
#pragma unroll
                for (int r = 0; r < st; ++r) u[r] += u[r + st];
            sum0 = u[0];
        }
#pragma unroll
        for (int c1 = 0; c1 < 2; ++c1) {
            unsigned int a0 = pk0[4 * c1 + 0], b0 = pk0[4 * c1 + 2];
            unsigned int a1 = pk0[4 * c1 + 1], b1 = pk0[4 * c1 + 3];
            asm("v_permlane32_swap_b32 %0, %1" : "+v"(a0), "+v"(b0));
            asm("v_permlane32_swap_b32 %0, %1" : "+v"(a1), "+v"(b1));
            union { unsigned int u[4]; bf16x8 v; } pb;
            pb.u[0] = a0; pb.u[1] = a1; pb.u[2] = b0; pb.u[3] = b1;
#pragma unroll
            for (int df = 0; df < 4; ++df) {
                bf16x8 va = *(const bf16x8*)(Kl + vrb[df] + xk[c1]);
                oa[df] = __builtin_amdgcn_mfma_f32_32x32x16_bf16(va, pb.v, oa[df], 0, 0, 0);
            }
        }

        // ---- half 1: exp + pack, then PV kc2=2,3 ----
#pragma unroll
        for (int r = 0; r < 16; ++r) s1[r] = exp2f(fmaf(s1[r], L2E, -mb));
        unsigned int pk1[8];
#pragma unroll
        for (int m = 0; m < 8; ++m) pk1[m] = pack2bf(s1[2 * m], s1[2 * m + 1]);
        {
            float u[8];
#pragma unroll
            for (int r = 0; r < 8; ++r) u[r] = s1[r] + s1[r + 8];
#pragma unroll
            for (int st = 4; st >= 1; st >>= 1)
#pragma unroll
                for (int r = 0; r < st; ++r) u[r] += u[r + st];
            sum1 = u[0];
        }
#pragma unroll
        for (int c1 = 0; c1 < 2; ++c1) {
            unsigned int a0 = pk1[4 * c1 + 0], b0 = pk1[4 * c1 + 2];
            unsigned int a1 = pk1[4 * c1 + 1], b1 = pk1[4 * c1 + 3];
            asm("v_permlane32_swap_b32 %0, %1" : "+v"(a0), "+v"(b0));
            asm("v_permlane32_swap_b32 %0, %1" : "+v"(a1), "+v"(b1));
            union { unsigned int u[4]; bf16x8 v; } pb;
            pb.u[0] = a0; pb.u[1] = a1; pb.u[2] = b0; pb.u[3] = b1;
#pragma unroll
            for (int df = 0; df < 4; ++df) {
                bf16x8 va = *(const bf16x8*)(Kl + vrb[df] + xk[2 + c1]);
                oa[df] = __builtin_amdgcn_mfma_f32_32x32x16_bf16(va, pb.v, oa[df], 0, 0, 0);
            }
        }

        float rs = sum0 + sum1;
        rs += __shfl_xor(rs, 32);
        l_run += rs;
        __syncthreads();
    }

    float inv = 1.f / l_run;
    bf16_t* Ot = (bf16_t*)((char*)lds + wid * 8704);
#pragma unroll
    for (int df = 0; df < 4; ++df)
#pragma unroll
        for (int rg = 0; rg < 4; ++rg) {
            bf16x4 w;
#pragma unroll
            for (int i = 0; i < 4; ++i) w[i] = (bf16_t)(oa[df][rg * 4 + i] * inv);
            int d0 = df * 32 + rg * 8 + hi * 4;
            *(bf16x4*)&Ot[ql * 136 + d0] = w;
        }
    __builtin_amdgcn_s_waitcnt(0);
    const int qloc = lane >> 1, half = lane & 1;
    const int b = bh >> 4, h = bh & 15;
    bf16_t* orow = outp + (size_t)(b * NTOK + q0 + wid * 32 + qloc) * HIDDEN + h * HD + half * 64;
    const bf16_t* src = Ot + qloc * 136 + half * 64;
#pragma unroll
    for (int c = 0; c < 8; ++c)
        *(bf16x8*)(orow + c * 8) = *(const bf16x8*)(src + c * 8);
}

extern "C" void kernel_launch(void* const* d_in, const int* in_sizes, int n_in,
                              void* d_out, int out_size, void* d_ws, size_t ws_size,
                              hipStream_t stream) {
    const float* x = (const float*)d_in[0];
    const float* w_qkv = (const float*)d_in[1];
    const float* b_qkv = (const float*)d_in[2];
    const float* w_proj = (const float*)d_in[3];
    const float* b_proj = (const float*)d_in[4];
    const int* Hp = (const int*)d_in[6];
    const int* Wp = (const int*)d_in[7];
    float* out = (float*)d_out;

    char* ws = (char*)d_ws;
    bf16_t* xb = (bf16_t*)(ws + 0);                       // 16 MiB  [4096][2048]
    bf16_t* wqkvT = (bf16_t*)(ws + 16777216);             // 24 MiB  [6144][2048]
    bf16_t* wprojT = (bf16_t*)(ws + 41943040);            // 8 MiB   [2048][2048]
    bf16_t* qkv = (bf16_t*)(ws + 50331648);               // 48 MiB  [4096][6144]
    bf16_t* qTb = (bf16_t*)(ws + 100663296);              // 16 MiB  [32][2048][128]
    bf16_t* kTb = (bf16_t*)(ws + 117440512);              // 16 MiB
    float2* tab = (float2*)(ws + 0);                      // 1 MiB, reuse xb after gemm1
    bf16_t* vT = (bf16_t*)(ws + 16777216);                // reuse wqkvT region after gemm1
    bf16_t* attno = (bf16_t*)(ws + 50331648);             // reuse qkv region after rope

    cvt8_kernel<<<4096, 256, 0, stream>>>(x, xb, 1048576);
    cvtT_kernel<<<dim3(96, 32), 256, 0, stream>>>(w_qkv, wqkvT, 2048, 6144);
    cvtT_kernel<<<dim3(32, 32), 256, 0, stream>>>(w_proj, wprojT, 2048, 2048);
    gemm_pipe<bf16_t><<<768, 256, 0, stream>>>(xb, wqkvT, b_qkv, qkv, MROWS, QKVCOLS, HIDDEN);
    rope_cs<<<512, 256, 0, stream>>>(Hp, Wp, tab);
    rope_fused<<<1024, 256, 0, stream>>>(qkv, qTb, kTb, vT, tab);
    attn_kernel<<<512, 256, 0, stream>>>(qTb, kTb, vT, attno);
    gemm_pipe_sq<<<512, 256, 0, stream>>>(attno, wprojT, b_proj, out, MROWS, HIDDEN, HIDDEN);
}